// Round 5
// baseline (130.940 us; speedup 1.0000x reference)
//
#include <hip/hip_runtime.h>

#define DDIM 1024
#define NEXP 64
#define TOPK 8
#define BK 32
#define ROWS 64
#define NTILE 32
#define TAUF 5.0e-3f
#define TAUB 1.0e-2f

typedef __attribute__((ext_vector_type(8))) short short8;
typedef __attribute__((ext_vector_type(4))) float f32x4;

static __device__ __forceinline__ unsigned int f2u(float f) { return __builtin_bit_cast(unsigned int, f); }
static __device__ __forceinline__ float u2f(unsigned int u) { return __builtin_bit_cast(float, u); }

static __device__ __forceinline__ unsigned short bf_hi_rne(float x) {
    unsigned int u = f2u(x);
    return (unsigned short)((u + (0x7FFFu + ((u >> 16) & 1u))) >> 16);
}

static __device__ __forceinline__ void split2(float x, unsigned short& h, unsigned short& l) {
    unsigned int u = f2u(x);
    unsigned int uh = (u + (0x7FFFu + ((u >> 16) & 1u))) & 0xFFFF0000u;
    h = (unsigned short)(uh >> 16);
    float rem = x - u2f(uh);
    l = (unsigned short)(f2u(rem) >> 16);
}

// Prologue: pre-permute W into per-(tile,wave) register-load order.
// tile t, wave q, array a (0=wn_hi,1=wn_lo,2=we_hi), lane l = c*16 + (e&15):
//   ws byte offset = t*12288 + q*3072 + a*1024 + l*16   (1KB contiguous per wave-array)
__global__ __launch_bounds__(256) void conv_w_kernel(
    const float* __restrict__ Wn, const float* __restrict__ We, char* __restrict__ wsW)
{
    int g = blockIdx.x * 256 + threadIdx.x;   // 0..8191
    int e = g >> 7, c128 = g & 127;
    int k = c128 << 3;
    int t = k >> 5, c = (k >> 3) & 3;
    const float* np = Wn + (size_t)e * DDIM + k;
    const float* ep = We + (size_t)e * DDIM + k;
    f32x4 n0 = ((const f32x4*)np)[0], n1 = ((const f32x4*)np)[1];
    f32x4 e0 = ((const f32x4*)ep)[0], e1 = ((const f32x4*)ep)[1];
    short8 nh, nl, eh;
#pragma unroll
    for (int i = 0; i < 4; i++) { unsigned short h, l; split2(n0[i], h, l); nh[i] = (short)h; nl[i] = (short)l; }
#pragma unroll
    for (int i = 0; i < 4; i++) { unsigned short h, l; split2(n1[i], h, l); nh[i + 4] = (short)h; nl[i + 4] = (short)l; }
#pragma unroll
    for (int i = 0; i < 4; i++) eh[i] = (short)bf_hi_rne(e0[i]);
#pragma unroll
    for (int i = 0; i < 4; i++) eh[i + 4] = (short)bf_hi_rne(e1[i]);
    size_t dst = (size_t)t * 12288 + (size_t)(e >> 4) * 3072 + (size_t)((c * 16 + (e & 15)) * 16);
    *(short8*)(wsW + dst)        = nh;
    *(short8*)(wsW + dst + 1024) = nl;
    *(short8*)(wsW + dst + 2048) = eh;
}

// LDS: x triple-buffer [3][64 rows][32 k] bf16-hi (12 KB, XOR-swizzled).
// Epilogue overlay: s_log[64][65] @0, s_exp @16640, s_gap @33280, s_vb @33536.
template <int PRE>
__global__ __launch_bounds__(256, 4) void moe_kernel(
    const float* __restrict__ x, const float* __restrict__ Wn,
    const float* __restrict__ bn, const float* __restrict__ We,
    const char* __restrict__ wsW, float* __restrict__ out)
{
    __shared__ __align__(16) char smem[33792];

    const int tid = threadIdx.x;
    const int wid = tid >> 6;
    const int lane = tid & 63;
    const int fr = lane & 15;
    const int fq = lane >> 4;
    const int blockRow = blockIdx.x * ROWS;

    // x staging role: thread covers row srow, 8-float chunk sg (coalesced 128B/row)
    const int srow = tid >> 2, sg = tid & 3;
    const int swz = (srow * 64 + sg * 16) ^ ((srow & 7) << 4);
    const float* xsrc = x + (size_t)(blockRow + srow) * DDIM + sg * 8;

    // named register sets (rule #20: no runtime indexing)
    f32x4 sxA0, sxA1, sxB0, sxB1, sxC0, sxC1;
    short8 whA, wlA, ehA, whB, wlB, ehB, whC, wlC, ehC;

    const char* wbase = wsW + wid * 3072 + lane * 16;

#define XLOAD_A(t) { const float* p = xsrc + (t) * BK; sxA0 = ((const f32x4*)p)[0]; sxA1 = ((const f32x4*)p)[1]; }
#define XLOAD_B(t) { const float* p = xsrc + (t) * BK; sxB0 = ((const f32x4*)p)[0]; sxB1 = ((const f32x4*)p)[1]; }
#define XLOAD_C(t) { const float* p = xsrc + (t) * BK; sxC0 = ((const f32x4*)p)[0]; sxC1 = ((const f32x4*)p)[1]; }

#define WLOAD(t, wh, wl, eh) { \
    if constexpr (PRE) { \
        const char* wp = wbase + (size_t)(t) * 12288; \
        wh = *(const short8*)(wp); \
        wl = *(const short8*)(wp + 1024); \
        eh = *(const short8*)(wp + 2048); \
    } else { \
        const float* np_ = Wn + (size_t)(wid * 16 + fr) * DDIM + (t) * BK + fq * 8; \
        const float* ep_ = We + (size_t)(wid * 16 + fr) * DDIM + (t) * BK + fq * 8; \
        f32x4 n0_ = ((const f32x4*)np_)[0], n1_ = ((const f32x4*)np_)[1]; \
        f32x4 e0_ = ((const f32x4*)ep_)[0], e1_ = ((const f32x4*)ep_)[1]; \
        for (int i = 0; i < 4; i++) { unsigned short h_, l_; split2(n0_[i], h_, l_); wh[i] = (short)h_; wl[i] = (short)l_; } \
        for (int i = 0; i < 4; i++) { unsigned short h_, l_; split2(n1_[i], h_, l_); wh[i + 4] = (short)h_; wl[i + 4] = (short)l_; } \
        for (int i = 0; i < 4; i++) eh[i] = (short)bf_hi_rne(e0_[i]); \
        for (int i = 0; i < 4; i++) eh[i + 4] = (short)bf_hi_rne(e1_[i]); \
    } }

#define STAGE_WRITE(b, s0, s1) { \
    short8 xh_; \
    for (int i = 0; i < 4; i++) xh_[i] = (short)bf_hi_rne(s0[i]); \
    for (int i = 0; i < 4; i++) xh_[i + 4] = (short)bf_hi_rne(s1[i]); \
    *(short8*)(smem + (b) * 4096 + swz) = xh_; }

    f32x4 accN[4], accE[4];
#pragma unroll
    for (int rt = 0; rt < 4; rt++) { accN[rt] = f32x4{0.f,0.f,0.f,0.f}; accE[rt] = f32x4{0.f,0.f,0.f,0.f}; }

#define COMPUTE(b, wh, wl, eh) { \
    const char* xb_ = smem + (b) * 4096; \
    _Pragma("unroll") \
    for (int rt = 0; rt < 4; rt++) { \
        const int row_ = rt * 16 + fr; \
        const int xoff_ = (row_ * 64 + fq * 16) ^ ((row_ & 7) << 4); \
        short8 xh_ = *(const short8*)(xb_ + xoff_); \
        accN[rt] = __builtin_amdgcn_mfma_f32_16x16x32_bf16(xh_, wh, accN[rt], 0, 0, 0); \
        accN[rt] = __builtin_amdgcn_mfma_f32_16x16x32_bf16(xh_, wl, accN[rt], 0, 0, 0); \
        accE[rt] = __builtin_amdgcn_mfma_f32_16x16x32_bf16(xh_, eh, accE[rt], 0, 0, 0); \
    } }

#define BAR() { asm volatile("s_waitcnt lgkmcnt(0)" ::: "memory"); \
                __builtin_amdgcn_s_barrier(); \
                asm volatile("" ::: "memory"); }

    // ---- prologue: fixed issue order (W before x at equal depth)
    WLOAD(0, whA, wlA, ehA); XLOAD_A(0);
    WLOAD(1, whB, wlB, ehB); XLOAD_B(1);
    WLOAD(2, whC, wlC, ehC); XLOAD_C(2);
    STAGE_WRITE(0, sxA0, sxA1);       // counted vmcnt wait for x0 only
    XLOAD_A(3);                       // x3 -> set A
    BAR();

    // ---- main loop, fully unrolled x3-pattern; vmcnt NEVER drained mid-loop.
    // iter t: COMPUTE(buf t%3, Wset t%3); stage-write x_{t+1} (set (t+1)%3 -> buf (t+1)%3);
    //         issue W_{t+3} into Wset t%3; issue x_{t+4} into xset (t+1)%3; barrier.
#define ITER(T, W_, X_) { \
        COMPUTE((T) % 3, wh##W_, wl##W_, eh##W_); \
        if ((T) + 1 < NTILE) { STAGE_WRITE(((T) + 1) % 3, sx##X_##0, sx##X_##1); } \
        if ((T) + 3 < NTILE) { WLOAD((T) + 3, wh##W_, wl##W_, eh##W_); } \
        if ((T) + 4 < NTILE) { XLOAD_##X_((T) + 4); } \
        if ((T) + 1 < NTILE) { BAR(); } \
    }

    ITER(0, A, B)  ITER(1, B, C)  ITER(2, C, A)
    ITER(3, A, B)  ITER(4, B, C)  ITER(5, C, A)
    ITER(6, A, B)  ITER(7, B, C)  ITER(8, C, A)
    ITER(9, A, B)  ITER(10, B, C) ITER(11, C, A)
    ITER(12, A, B) ITER(13, B, C) ITER(14, C, A)
    ITER(15, A, B) ITER(16, B, C) ITER(17, C, A)
    ITER(18, A, B) ITER(19, B, C) ITER(20, C, A)
    ITER(21, A, B) ITER(22, B, C) ITER(23, C, A)
    ITER(24, A, B) ITER(25, B, C) ITER(26, C, A)
    ITER(27, A, B) ITER(28, B, C) ITER(29, C, A)
    ITER(30, A, B) ITER(31, B, C)
    __syncthreads();

    // ---- epilogue overlay
    float* s_log = (float*)smem;                 // [64][65]
    float* s_exp = (float*)(smem + 16640);       // [64][65]
    float* s_gap = (float*)(smem + 33280);       // [64]
    float* s_vb  = (float*)(smem + 33536);       // [64]

    const int ecol = wid * 16 + fr;
    const float be = bn[ecol];
#pragma unroll
    for (int rt = 0; rt < 4; rt++) {
#pragma unroll
        for (int j = 0; j < 4; j++) {
            const int r = rt * 16 + fq * 4 + j;  // C/D: col=lane&15, row=(lane>>4)*4+j
            s_log[r * 65 + ecol] = accN[rt][j] + be;
            s_exp[r * 65 + ecol] = accE[rt][j];
        }
    }
    __syncthreads();

    auto do_row = [&](int r, float& gapo, float& vbo) -> float {
        float selv[TOPK]; int seli[TOPK];
        unsigned long long chosen = 0ull;
#pragma unroll
        for (int t = 0; t < TOPK; t++) {
            float best = -3.0e38f; int bi = 0;
#pragma unroll 4
            for (int e = 0; e < NEXP; e++) {
                float v = s_log[r * 65 + e];
                if (!((chosen >> e) & 1ull) && v > best) { best = v; bi = e; }  // strict > => lowest idx on ties
            }
            selv[t] = best; seli[t] = bi; chosen |= (1ull << bi);
        }
        float v9 = -3.0e38f;
#pragma unroll 4
        for (int e = 0; e < NEXP; e++) {
            float v = s_log[r * 65 + e];
            if (!((chosen >> e) & 1ull) && v > v9) v9 = v;
        }
        gapo = selv[TOPK - 1] - v9;
        vbo = 0.5f * (selv[TOPK - 1] + v9);
        float m = selv[0], Z = 0.f, o = 0.f;
#pragma unroll
        for (int t = 0; t < TOPK; t++) {
            float w = __expf(selv[t] - m);
            Z += w;
            o += w * s_exp[r * 65 + seli[t]];
        }
        return o / Z;
    };

    // selection: wave w owns rows [w*16, w*16+16), one row per lane (lanes 0-15)
    if (lane < 16) {
        const int r = wid * 16 + lane;
        float gap, vb;
        float res = do_row(r, gap, vb);
        out[blockRow + r] = res;
        s_gap[r] = gap; s_vb[r] = vb;
    }
    __syncthreads();

    // fp64 fixup for near-tie rows, distributed: wave w handles rows r%4==w
    for (int r = wid; r < ROWS; r += 4) {
        if (!(s_gap[r] < TAUF)) continue;
        const float vbr = s_vb[r];
        const float ve = s_log[r * 65 + lane];
        unsigned long long cand = __ballot(fabsf(ve - vbr) <= TAUB);
        const f32x4* xq = (const f32x4*)(x + (size_t)(blockRow + r) * DDIM) + lane * 4;
        const f32x4 xv0 = xq[0], xv1 = xq[1], xv2 = xq[2], xv3 = xq[3];
        while (cand) {
            const int ce = __builtin_ctzll(cand);
            cand &= cand - 1;
            const f32x4* wq = (const f32x4*)(Wn + (size_t)ce * DDIM) + lane * 4;
            const f32x4 w0 = wq[0], w1 = wq[1], w2 = wq[2], w3 = wq[3];
            double s = 0.0;
#pragma unroll
            for (int i = 0; i < 4; i++) s = fma((double)xv0[i], (double)w0[i], s);
#pragma unroll
            for (int i = 0; i < 4; i++) s = fma((double)xv1[i], (double)w1[i], s);
#pragma unroll
            for (int i = 0; i < 4; i++) s = fma((double)xv2[i], (double)w2[i], s);
#pragma unroll
            for (int i = 0; i < 4; i++) s = fma((double)xv3[i], (double)w3[i], s);
#pragma unroll
            for (int off = 32; off > 0; off >>= 1) s += __shfl_xor(s, off);
            s += (double)bn[ce];
            if (lane == 0) s_log[r * 65 + ce] = (float)s;
        }
    }
    __syncthreads();

    // re-select flagged rows with corrected logits
    if (lane < 16) {
        const int r = wid * 16 + lane;
        if (s_gap[r] < TAUF) {
            float g2, v2;
            out[blockRow + r] = do_row(r, g2, v2);
        }
    }
}

extern "C" void kernel_launch(void* const* d_in, const int* in_sizes, int n_in,
                              void* d_out, int out_size, void* d_ws, size_t ws_size,
                              hipStream_t stream)
{
    // setup_inputs order: x, Wg, bg, Wn, bn, We, noise  (Wg/bg/noise are dead code)
    const float* x  = (const float*)d_in[0];
    const float* Wn = (const float*)d_in[3];
    const float* bn = (const float*)d_in[4];
    const float* We = (const float*)d_in[5];
    float* out = (float*)d_out;

    const int B = in_sizes[0] / DDIM;           // 65536
    const int grid = B / ROWS;                  // 1024

    const size_t need = (size_t)NTILE * 12288;  // 384 KiB permuted W
    if (d_ws != nullptr && ws_size >= need) {
        conv_w_kernel<<<(NEXP * DDIM / 8) / 256, 256, 0, stream>>>(Wn, We, (char*)d_ws);
        moe_kernel<1><<<grid, 256, 0, stream>>>(x, Wn, bn, We, (const char*)d_ws, out);
    } else {
        moe_kernel<0><<<grid, 256, 0, stream>>>(x, Wn, bn, We, nullptr, out);
    }
}

// Round 6
// 127.508 us; speedup vs baseline: 1.0269x; 1.0269x over previous
//
#include <hip/hip_runtime.h>

#define DDIM 1024
#define NEXP 64
#define TOPK 8
#define BK 32
#define ROWS 64
#define NTILE 32
#define WTILE 12288
#define TAUF 5.0e-3f
#define TAUB 1.0e-2f

typedef __attribute__((ext_vector_type(8))) short short8;
typedef __attribute__((ext_vector_type(4))) float f32x4;

static __device__ __forceinline__ unsigned int f2u(float f) { return __builtin_bit_cast(unsigned int, f); }
static __device__ __forceinline__ float u2f(unsigned int u) { return __builtin_bit_cast(float, u); }

static __device__ __forceinline__ unsigned short bf_hi_rne(float x) {
    unsigned int u = f2u(x);
    return (unsigned short)((u + (0x7FFFu + ((u >> 16) & 1u))) >> 16);
}

static __device__ __forceinline__ void split2(float x, unsigned short& h, unsigned short& l) {
    unsigned int u = f2u(x);
    unsigned int uh = (u + (0x7FFFu + ((u >> 16) & 1u))) & 0xFFFF0000u;
    h = (unsigned short)(uh >> 16);
    float rem = x - u2f(uh);
    l = (unsigned short)(f2u(rem) >> 16);
}

// Prologue: pre-permute W into the (swizzled) LDS image the main kernel DMAs linearly.
// tile t, array a (0=wn_hi,1=wn_lo,2=we_hi), expert e, 16B chunk c (k = t*32 + c*8):
//   ws byte = t*12288 + a*4096 + ((e*64 + c*16) ^ ((e&7)<<4))
__global__ __launch_bounds__(256) void conv_w_kernel(
    const float* __restrict__ Wn, const float* __restrict__ We, char* __restrict__ wsW)
{
    int g = blockIdx.x * 256 + threadIdx.x;   // 0..8191
    int e = g >> 7, c128 = g & 127;
    int k = c128 << 3;
    int t = k >> 5, c = (k >> 3) & 3;
    const float* np = Wn + (size_t)e * DDIM + k;
    const float* ep = We + (size_t)e * DDIM + k;
    f32x4 n0 = ((const f32x4*)np)[0], n1 = ((const f32x4*)np)[1];
    f32x4 e0 = ((const f32x4*)ep)[0], e1 = ((const f32x4*)ep)[1];
    short8 nh, nl, eh;
#pragma unroll
    for (int i = 0; i < 4; i++) { unsigned short h, l; split2(n0[i], h, l); nh[i] = (short)h; nl[i] = (short)l; }
#pragma unroll
    for (int i = 0; i < 4; i++) { unsigned short h, l; split2(n1[i], h, l); nh[i + 4] = (short)h; nl[i + 4] = (short)l; }
#pragma unroll
    for (int i = 0; i < 4; i++) eh[i] = (short)bf_hi_rne(e0[i]);
#pragma unroll
    for (int i = 0; i < 4; i++) eh[i + 4] = (short)bf_hi_rne(e1[i]);
    size_t dst = (size_t)t * WTILE + (size_t)((e * 64 + c * 16) ^ ((e & 7) << 4));
    *(short8*)(wsW + dst)        = nh;
    *(short8*)(wsW + dst + 4096) = nl;
    *(short8*)(wsW + dst + 8192) = eh;
}

// LDS (36864 B -> 4 blocks/CU): W triple-buffer, 3 x 12288 (wn_hi|wn_lo|we_hi, 4KB each).
// Epilogue overlay: s_log[64][65] @0, s_exp @16640, s_gap @33280, s_vb @33536.
// x never touches LDS: per-lane A-fragment loads, 3-deep named register sets.
template <int PRE>
__global__ __launch_bounds__(256, 4) void moe_kernel(
    const float* __restrict__ x, const float* __restrict__ Wn,
    const float* __restrict__ bn, const float* __restrict__ We,
    const char* __restrict__ wsW, float* __restrict__ out)
{
    __shared__ __align__(16) char smem[36864];

    const int tid = threadIdx.x;
    const int wid = tid >> 6;          // wave owns rows wid*16 .. +15, ALL 64 experts
    const int lane = tid & 63;
    const int fr = lane & 15;          // A-row within wave tile / C col (expert-local)
    const int fq = lane >> 4;          // k-quadrant
    const int blockRow = blockIdx.x * ROWS;

    // per-lane x source: row blockRow + wid*16 + fr, k chunk fq*8
    const float* xsrc = x + (size_t)(blockRow + wid * 16 + fr) * DDIM + fq * 8;
    // swizzled W ds_read offset (lane part); per (array a, col-tile ct): + a*4096 + ct*1024
    const int xo = (fr * 64 + fq * 16) ^ ((fr & 7) << 4);

    f32x4 sxA0, sxA1, sxB0, sxB1, sxC0, sxC1;   // 3 named x sets (rule #20)

    f32x4 accN[4], accE[4];
#pragma unroll
    for (int ct = 0; ct < 4; ct++) { accN[ct] = f32x4{0.f,0.f,0.f,0.f}; accE[ct] = f32x4{0.f,0.f,0.f,0.f}; }

#define XLOAD(S, T) { const float* p_ = xsrc + (T) * BK; \
    sx##S##0 = ((const f32x4*)p_)[0]; sx##S##1 = ((const f32x4*)p_)[1]; }

#define WDMA(T, WB) { \
    const char* gs_ = wsW + (size_t)(T) * WTILE + wid * 1024 + lane * 16; \
    char* ls_ = smem + (WB) * WTILE + wid * 1024; \
    _Pragma("unroll") \
    for (int a_ = 0; a_ < 3; a_++) \
        __builtin_amdgcn_global_load_lds( \
            (const __attribute__((address_space(1))) void*)(gs_ + a_ * 4096), \
            (__attribute__((address_space(3))) void*)(ls_ + a_ * 4096), 16, 0, 0); }

// One K-tile: convert x(set S) -> A-frag, refill S with x(T+3) if DOX, 12 ds_read + 12 MFMA,
// then lgkmcnt(0) (reg safety before buffer reuse) + counted VMSTR + barrier + DMA W(T+3).
#define ITER(T, WB, S, DOX, DODMA, VMSTR) { \
    short8 xh_; \
    _Pragma("unroll") for (int i = 0; i < 4; i++) xh_[i]     = (short)bf_hi_rne(sx##S##0[i]); \
    _Pragma("unroll") for (int i = 0; i < 4; i++) xh_[i + 4] = (short)bf_hi_rne(sx##S##1[i]); \
    if (DOX) { XLOAD(S, (T) + 3); } \
    const char* wb_ = smem + (WB) * WTILE + xo; \
    _Pragma("unroll") \
    for (int ct = 0; ct < 4; ct++) { \
        short8 wh_, wl_, eh_; \
        if constexpr (PRE) { \
            wh_ = *(const short8*)(wb_ + ct * 1024); \
            wl_ = *(const short8*)(wb_ + 4096 + ct * 1024); \
            eh_ = *(const short8*)(wb_ + 8192 + ct * 1024); \
        } else { \
            const float* np_ = Wn + (size_t)(ct * 16 + fr) * DDIM + (T) * BK + fq * 8; \
            const float* ep_ = We + (size_t)(ct * 16 + fr) * DDIM + (T) * BK + fq * 8; \
            f32x4 n0_ = ((const f32x4*)np_)[0], n1_ = ((const f32x4*)np_)[1]; \
            f32x4 e0_ = ((const f32x4*)ep_)[0], e1_ = ((const f32x4*)ep_)[1]; \
            for (int i = 0; i < 4; i++) { unsigned short h_, l_; split2(n0_[i], h_, l_); wh_[i] = (short)h_; wl_[i] = (short)l_; } \
            for (int i = 0; i < 4; i++) { unsigned short h_, l_; split2(n1_[i], h_, l_); wh_[i + 4] = (short)h_; wl_[i + 4] = (short)l_; } \
            for (int i = 0; i < 4; i++) eh_[i] = (short)bf_hi_rne(e0_[i]); \
            for (int i = 0; i < 4; i++) eh_[i + 4] = (short)bf_hi_rne(e1_[i]); \
        } \
        accN[ct] = __builtin_amdgcn_mfma_f32_16x16x32_bf16(xh_, wh_, accN[ct], 0, 0, 0); \
        accN[ct] = __builtin_amdgcn_mfma_f32_16x16x32_bf16(xh_, wl_, accN[ct], 0, 0, 0); \
        accE[ct] = __builtin_amdgcn_mfma_f32_16x16x32_bf16(xh_, eh_, accE[ct], 0, 0, 0); \
    } \
    asm volatile("s_waitcnt lgkmcnt(0)\ns_waitcnt " VMSTR ::: "memory"); \
    __builtin_amdgcn_s_barrier(); \
    asm volatile("" ::: "memory"); \
    if constexpr (PRE) { if (DODMA) { WDMA((T) + 3, WB); } } }

    // ---- prologue: x(0..2) then W(0..2); vmcnt(6) ensures W(0) (leaves W1,W2 in flight)
    XLOAD(A, 0); XLOAD(B, 1); XLOAD(C, 2);
    if constexpr (PRE) {
        WDMA(0, 0); WDMA(1, 1); WDMA(2, 2);
        asm volatile("s_waitcnt vmcnt(6)" ::: "memory");
    }
    __builtin_amdgcn_s_barrier();
    asm volatile("" ::: "memory");

    // ---- first triple (t=0 needs vmcnt(5): after W(1) only W(2):3 + x(3):2 outstanding)
    ITER(0, 0, A, 1, 1, "vmcnt(5)")
    ITER(1, 1, B, 1, 1, "vmcnt(7)")
    ITER(2, 2, C, 1, 1, "vmcnt(7)")
    // ---- steady state t=3..26 (8 triples); W(t+1) wait = vmcnt(7)
#pragma unroll 1
    for (int p = 1; p < 9; ++p) {
        const int t0 = 3 * p;
        ITER(t0 + 0, 0, A, 1, 1, "vmcnt(7)")
        ITER(t0 + 1, 1, B, 1, 1, "vmcnt(7)")
        ITER(t0 + 2, 2, C, 1, 1, "vmcnt(7)")
    }
    // ---- tail peel t=27..31 (drain)
    ITER(27, 0, A, 1, 1, "vmcnt(7)")   // loads x(30), DMA W(30)
    ITER(28, 1, B, 1, 1, "vmcnt(7)")   // loads x(31), DMA W(31)
    ITER(29, 2, C, 0, 0, "vmcnt(5)")   // ensure W(30): x(31):2 + W(31):3 newer
    ITER(30, 0, A, 0, 0, "vmcnt(0)")   // ensure W(31): nothing newer
    { // t=31: compute only
        short8 xh_;
#pragma unroll
        for (int i = 0; i < 4; i++) xh_[i]     = (short)bf_hi_rne(sxB0[i]);
#pragma unroll
        for (int i = 0; i < 4; i++) xh_[i + 4] = (short)bf_hi_rne(sxB1[i]);
        const char* wb_ = smem + 1 * WTILE + xo;
#pragma unroll
        for (int ct = 0; ct < 4; ct++) {
            short8 wh_, wl_, eh_;
            if constexpr (PRE) {
                wh_ = *(const short8*)(wb_ + ct * 1024);
                wl_ = *(const short8*)(wb_ + 4096 + ct * 1024);
                eh_ = *(const short8*)(wb_ + 8192 + ct * 1024);
            } else {
                const float* np_ = Wn + (size_t)(ct * 16 + fr) * DDIM + 31 * BK + fq * 8;
                const float* ep_ = We + (size_t)(ct * 16 + fr) * DDIM + 31 * BK + fq * 8;
                f32x4 n0_ = ((const f32x4*)np_)[0], n1_ = ((const f32x4*)np_)[1];
                f32x4 e0_ = ((const f32x4*)ep_)[0], e1_ = ((const f32x4*)ep_)[1];
                for (int i = 0; i < 4; i++) { unsigned short h_, l_; split2(n0_[i], h_, l_); wh_[i] = (short)h_; wl_[i] = (short)l_; }
                for (int i = 0; i < 4; i++) { unsigned short h_, l_; split2(n1_[i], h_, l_); wh_[i + 4] = (short)h_; wl_[i + 4] = (short)l_; }
                for (int i = 0; i < 4; i++) eh_[i] = (short)bf_hi_rne(e0_[i]);
                for (int i = 0; i < 4; i++) eh_[i + 4] = (short)bf_hi_rne(e1_[i]);
            }
            accN[ct] = __builtin_amdgcn_mfma_f32_16x16x32_bf16(xh_, wh_, accN[ct], 0, 0, 0);
            accN[ct] = __builtin_amdgcn_mfma_f32_16x16x32_bf16(xh_, wl_, accN[ct], 0, 0, 0);
            accE[ct] = __builtin_amdgcn_mfma_f32_16x16x32_bf16(xh_, eh_, accE[ct], 0, 0, 0);
        }
    }
    __syncthreads();

    // ---- epilogue overlay
    float* s_log = (float*)smem;                 // [64][65]
    float* s_exp = (float*)(smem + 16640);       // [64][65]
    float* s_gap = (float*)(smem + 33280);       // [64]
    float* s_vb  = (float*)(smem + 33536);       // [64]

    // C/D: col = lane&15 (expert-local), row = fq*4 + j (row-local within wave tile)
#pragma unroll
    for (int ct = 0; ct < 4; ct++) {
        const int e = ct * 16 + fr;
        const float be = bn[e];
#pragma unroll
        for (int j = 0; j < 4; j++) {
            const int r = wid * 16 + fq * 4 + j;
            s_log[r * 65 + e] = accN[ct][j] + be;
            s_exp[r * 65 + e] = accE[ct][j];
        }
    }
    __syncthreads();

    auto wave_max = [&](float c) {
#pragma unroll
        for (int off = 32; off >= 1; off >>= 1) c = fmaxf(c, __shfl_xor(c, off));
        return c;
    };
    auto wave_sum = [&](float c) {
#pragma unroll
        for (int off = 32; off >= 1; off >>= 1) c += __shfl_xor(c, off);
        return c;
    };

    // array-free wave-parallel top-8 + softmax + weighted sum; one row per pass.
    auto select_row = [&](int r, bool writeGap) {
        const float v = s_log[r * 65 + lane];
        const float g = s_exp[r * 65 + lane];
        unsigned long long act = ~0ull, sel = 0ull;
        float m0 = 0.f, v8 = 0.f;
#pragma unroll
        for (int tt = 0; tt < TOPK; tt++) {
            float c = ((act >> lane) & 1ull) ? v : -3.0e38f;
            c = wave_max(c);
            unsigned long long elig = __ballot(v == c) & act;   // lowest index wins ties
            int win = __builtin_ctzll(elig);
            sel |= 1ull << win;
            act &= ~(1ull << win);
            if (tt == 0) m0 = c;
            v8 = c;
        }
        float c9 = ((act >> lane) & 1ull) ? v : -3.0e38f;
        float v9 = wave_max(c9);
        float w = ((sel >> lane) & 1ull) ? __expf(v - m0) : 0.f;
        float Z = wave_sum(w);
        float O = wave_sum(w * g);
        if (lane == 0) {
            out[blockRow + r] = O / Z;
            if (writeGap) { s_gap[r] = v8 - v9; s_vb[r] = 0.5f * (v8 + v9); }
        }
    };

    for (int rr = 0; rr < 16; ++rr) select_row(wid * 16 + rr, true);
    __syncthreads();

    // fp64 fixup for near-tie rows, distributed: wave w handles rows r%4==w
    for (int r = wid; r < ROWS; r += 4) {
        if (!(s_gap[r] < TAUF)) continue;
        const float vbr = s_vb[r];
        const float ve = s_log[r * 65 + lane];
        unsigned long long cand = __ballot(fabsf(ve - vbr) <= TAUB);
        const f32x4* xq = (const f32x4*)(x + (size_t)(blockRow + r) * DDIM) + lane * 4;
        const f32x4 xv0 = xq[0], xv1 = xq[1], xv2 = xq[2], xv3 = xq[3];
        while (cand) {
            const int ce = __builtin_ctzll(cand);
            cand &= cand - 1;
            const f32x4* wq = (const f32x4*)(Wn + (size_t)ce * DDIM) + lane * 4;
            const f32x4 w0 = wq[0], w1 = wq[1], w2 = wq[2], w3 = wq[3];
            double s = 0.0;
#pragma unroll
            for (int i = 0; i < 4; i++) s = fma((double)xv0[i], (double)w0[i], s);
#pragma unroll
            for (int i = 0; i < 4; i++) s = fma((double)xv1[i], (double)w1[i], s);
#pragma unroll
            for (int i = 0; i < 4; i++) s = fma((double)xv2[i], (double)w2[i], s);
#pragma unroll
            for (int i = 0; i < 4; i++) s = fma((double)xv3[i], (double)w3[i], s);
#pragma unroll
            for (int off = 32; off > 0; off >>= 1) s += __shfl_xor(s, off);
            s += (double)bn[ce];
            if (lane == 0) s_log[r * 65 + ce] = (float)s;
        }
    }
    __syncthreads();

    // re-select flagged rows with corrected logits
    for (int rr = 0; rr < 16; ++rr) {
        const int r = wid * 16 + rr;
        if (s_gap[r] < TAUF) select_row(r, false);
    }
}

extern "C" void kernel_launch(void* const* d_in, const int* in_sizes, int n_in,
                              void* d_out, int out_size, void* d_ws, size_t ws_size,
                              hipStream_t stream)
{
    // setup_inputs order: x, Wg, bg, Wn, bn, We, noise  (Wg/bg/noise are dead code)
    const float* x  = (const float*)d_in[0];
    const float* Wn = (const float*)d_in[3];
    const float* bn = (const float*)d_in[4];
    const float* We = (const float*)d_in[5];
    float* out = (float*)d_out;

    const int B = in_sizes[0] / DDIM;           // 65536
    const int grid = B / ROWS;                  // 1024

    const size_t need = (size_t)NTILE * WTILE;  // 384 KiB permuted W
    if (d_ws != nullptr && ws_size >= need) {
        conv_w_kernel<<<(NEXP * DDIM / 8) / 256, 256, 0, stream>>>(Wn, We, (char*)d_ws);
        moe_kernel<1><<<grid, 256, 0, stream>>>(x, Wn, bn, We, (const char*)d_ws, out);
    } else {
        moe_kernel<0><<<grid, 256, 0, stream>>>(x, Wn, bn, We, nullptr, out);
    }
}